// Round 4
// baseline (359.383 us; speedup 1.0000x reference)
//
#include <hip/hip_runtime.h>

#define B_ 8
#define C_ 192
#define N_ 13824     // 24^3
#define HEADS 6
#define HD 32
#define THREEC 576
#define CHUNKS 24    // K2 n-chunks per (b,h): 576 n each, 9 phases of 64

typedef unsigned short ushort_t;
typedef unsigned int uint_t;
typedef __attribute__((ext_vector_type(8))) _Float16 half8;
typedef __attribute__((ext_vector_type(4))) float f32x4;

// fp16 (not bf16): same MFMA rate / bytes / layout, 8x lower rounding error.
__device__ __forceinline__ float h2f(ushort_t u) {
  union { ushort_t u; _Float16 h; } c; c.u = u; return (float)c.h;
}
__device__ __forceinline__ ushort_t f2h(float f) {
  union { _Float16 h; ushort_t u; } c; c.h = (_Float16)f; return c.u;  // v_cvt_f16_f32, RNE
}

// LDS row stride for fp16 tiles: 200 shorts = 100 dwords. 100 % 32 = 4, so
// fragment ds_read_b128 (16 lanes stepping rows) spreads 8 lanes/bank-quad.
#define LROW 200

// Lane->unit permutation for staging writes: unit u of row r goes to lane with
// ul = (u + r%8) % 24, so write bank-quad = ul%8 is uniform over the wave.
__device__ __forceinline__ void rowperm(int f, int& row, int& u) {
  row = f / 24;
  int ul = f - row * 24;
  int uu = ul - (row & 7);
  u = uu + ((uu < 0) ? 24 : 0);
}

// ---------------------------------------------------------------------------
// K0a: qkv_w fp32 -> fp16. grid 54.
// ---------------------------------------------------------------------------
__global__ __launch_bounds__(256) void wconv(const float* __restrict__ w,
                                             ushort_t* __restrict__ wbf) {
  int idx = (blockIdx.x * 256 + threadIdx.x) * 8;  // 54*256*8 = 110592
  float4 v0 = *(const float4*)&w[idx];
  float4 v1 = *(const float4*)&w[idx + 4];
  union { ushort_t us[8]; uint4 v; } pk;
  pk.us[0] = f2h(v0.x); pk.us[1] = f2h(v0.y); pk.us[2] = f2h(v0.z); pk.us[3] = f2h(v0.w);
  pk.us[4] = f2h(v1.x); pk.us[5] = f2h(v1.y); pk.us[6] = f2h(v1.z); pk.us[7] = f2h(v1.w);
  *(uint4*)&wbf[idx] = pk.v;
}

// ---------------------------------------------------------------------------
// K0b: transpose+convert x[b][c][n] fp32 -> xT[b][n][c] fp16. grid (216, 8).
// ---------------------------------------------------------------------------
__global__ __launch_bounds__(256) void xt_conv(const float* __restrict__ x,
                                               ushort_t* __restrict__ xT) {
  __shared__ ushort_t tile[64 * 200];
  int t = threadIdx.x;
  int n0 = blockIdx.x * 64, b = blockIdx.y;
  const float* xb = x + (size_t)b * C_ * N_;
  int n4 = t & 15, cp = t >> 4;
#pragma unroll
  for (int it = 0; it < 6; ++it) {
    int c = (cp + it * 16) * 2;
    float4 v0 = *(const float4*)&xb[(size_t)c * N_ + n0 + n4 * 4];
    float4 v1 = *(const float4*)&xb[(size_t)(c + 1) * N_ + n0 + n4 * 4];
    float a0[4] = {v0.x, v0.y, v0.z, v0.w};
    float a1[4] = {v1.x, v1.y, v1.z, v1.w};
#pragma unroll
    for (int i = 0; i < 4; ++i) {
      uint_t wd = (uint_t)f2h(a0[i]) | ((uint_t)f2h(a1[i]) << 16);
      *(uint_t*)&tile[(n4 * 4 + i) * 200 + c] = wd;
    }
  }
  __syncthreads();
  ushort_t* xTb = xT + ((size_t)b * N_ + n0) * C_;
  int r = t >> 2, q = t & 3;
#pragma unroll
  for (int j = 0; j < 6; ++j) {
    int chunk = q * 6 + j;
    uint4 v = *(const uint4*)&tile[r * 200 + chunk * 8];
    *(uint4*)&xTb[r * 192 + chunk * 8] = v;
  }
}

// ---------------------------------------------------------------------------
// K1: MFMA fp16 GEMM: qkv[b][o][n] = sum_c wbf[o][c]*xT[b][n][c] + bias[o].
// RESTRUCTURED: each block owns ONE n-tile (BN=128), stages it to LDS ONCE,
// then loops over ALL 9 o-blocks (A-fragments double-buffered from L2-resident
// wbf). 432 MFMA/block, ONE barrier total -> amortizes the measured ~6.3us
// fixed per-block cost ~9x. grid 864 = 8*108 (each XCD = one batch).
// ---------------------------------------------------------------------------
__global__ __launch_bounds__(256) void qkv_gemm_mfma(
    const ushort_t* __restrict__ wbf, const ushort_t* __restrict__ xT,
    const float* __restrict__ bias, ushort_t* __restrict__ qkv) {
  __shared__ ushort_t Bs[128 * LROW];  // [n][c], 51.2 KB -> 3 blocks/CU
  int t = threadIdx.x;
  int bid = blockIdx.x;
  int l = (bid & 7) * 108 + (bid >> 3);
  int n0 = (l % 108) * 128;
  int b = l / 108;
  int w = t >> 6, lane = t & 63;
  int ln16 = lane & 15, q4 = lane >> 4;
  int mrow = (w >> 1) * 32, ncol = (w & 1) * 64;

  const ushort_t* Bsrc = xT + ((size_t)b * N_ + n0) * C_;

  // ---- stage B once: 128 rows x 192 ch = 3072 16B units, 12/thread ----
  uint4 breg2[12]; int brow[12], bu[12];
#pragma unroll
  for (int j = 0; j < 12; ++j) {
    int f = (w * 12 + j) * 64 + lane;
    rowperm(f, brow[j], bu[j]);
    breg2[j] = *(const uint4*)(Bsrc + brow[j] * C_ + bu[j] * 8);
  }
#pragma unroll
  for (int j = 0; j < 12; ++j)
    *(uint4*)&Bs[brow[j] * LROW + bu[j] * 8] = breg2[j];

  // ---- A fragments for o-iter 0, issued before the barrier ----
  const ushort_t* Abase0 = wbf + (size_t)(mrow + ln16) * C_ + q4 * 8;
  half8 af[2][12];
#pragma unroll
  for (int kk = 0; kk < 6; ++kk)
#pragma unroll
    for (int mi = 0; mi < 2; ++mi)
      af[0][kk * 2 + mi] = *(const half8*)(Abase0 + mi * 16 * C_ + kk * 32);

  __syncthreads();  // the only barrier: Bs is read-only afterwards

#pragma unroll
  for (int it = 0; it < 9; ++it) {
    int o0 = it * 64;
    int cur = it & 1, nxt = cur ^ 1;
    if (it < 8) {  // prefetch next o-block's A fragments (hidden under MFMAs)
      const ushort_t* An = Abase0 + (size_t)(o0 + 64) * C_;
#pragma unroll
      for (int kk = 0; kk < 6; ++kk)
#pragma unroll
        for (int mi = 0; mi < 2; ++mi)
          af[nxt][kk * 2 + mi] = *(const half8*)(An + mi * 16 * C_ + kk * 32);
    }

    float breg[2][4];
#pragma unroll
    for (int mi = 0; mi < 2; ++mi)
#pragma unroll
      for (int r = 0; r < 4; ++r)
        breg[mi][r] = bias[o0 + mrow + mi * 16 + q4 * 4 + r];

    f32x4 acc[2][4];
#pragma unroll
    for (int mi = 0; mi < 2; ++mi)
#pragma unroll
      for (int ni = 0; ni < 4; ++ni) acc[mi][ni] = (f32x4){0.f, 0.f, 0.f, 0.f};

#pragma unroll
    for (int kk = 0; kk < 6; ++kk) {
      int k0 = kk * 32 + q4 * 8;
      half8 bb[4];
#pragma unroll
      for (int ni = 0; ni < 4; ++ni)
        bb[ni] = *(const half8*)&Bs[(ncol + ni * 16 + ln16) * LROW + k0];
#pragma unroll
      for (int mi = 0; mi < 2; ++mi)
#pragma unroll
        for (int ni = 0; ni < 4; ++ni)
          acc[mi][ni] = __builtin_amdgcn_mfma_f32_16x16x32_f16(
              af[cur][kk * 2 + mi], bb[ni], acc[mi][ni], 0, 0, 0);
    }

    // epilogue: +bias, fp16, pack n-pairs via shfl, b32 stores
#pragma unroll
    for (int mi = 0; mi < 2; ++mi)
#pragma unroll
      for (int ni = 0; ni < 4; ++ni)
#pragma unroll
        for (int r = 0; r < 4; ++r) {
          float v = acc[mi][ni][r] + breg[mi][r];
          uint_t bf = f2h(v);
          uint_t pv = (uint_t)__shfl_xor((int)bf, 1);
          if (!(lane & 1)) {
            int o_l = o0 + mrow + mi * 16 + q4 * 4 + r;
            int n_l = ncol + ni * 16 + ln16;
            *(uint_t*)&qkv[(size_t)(b * THREEC + o_l) * N_ + n0 + n_l] =
                bf | (pv << 16);
          }
        }
  }
}

// ---------------------------------------------------------------------------
// K2: per (b,h,chunk): partial S[c][d], nq[c], nk[d]. grid (24, 6, 8).
// Loads vectorized: uint4 (16B/lane, 8 channels) with a 2-phase pipeline;
// LDS row stride 36 floats (bank-spread, 16B-aligned). fp32 math unchanged.
// ---------------------------------------------------------------------------
__global__ __launch_bounds__(256) void attn_partial(
    const ushort_t* __restrict__ qkv, float* __restrict__ Spart) {
  __shared__ float sh[5120];  // q[64][36]=2304 | k at 2304 | sq 4608 | sk 4864
  int t = threadIdx.x;
  int chunk = blockIdx.x, h = blockIdx.y, b = blockIdx.z;
  int j = t & 31, g8 = t >> 5;
  int tg = t >> 6, tl = t & 63;
  int c0 = (tl & 7) * 4, d0 = (tl >> 3) * 4;
  int lrow = t >> 2, loct = t & 3;  // load: row 0..63, j-octet 0..3
  float acc[4][4];
#pragma unroll
  for (int i = 0; i < 4; ++i)
#pragma unroll
    for (int m = 0; m < 4; ++m) acc[i][m] = 0.f;
  float sqq = 0.f, sqk = 0.f;
  const ushort_t* basep = qkv + (size_t)b * THREEC * N_;
  int n2base = chunk * 576;

  // preload phase 0
  uint4 qv4, kv4;
  {
    int n2 = n2base + lrow;
    int o = n2 / 24, r = n2 - o * 24;
    const ushort_t* rp = basep + (size_t)o * N_ + r * THREEC + h * HD + loct * 8;
    qv4 = *(const uint4*)rp;
    kv4 = *(const uint4*)(rp + C_);
  }

  for (int p = 0; p < 9; ++p) {
    __syncthreads();  // prior phase's LDS reads complete
    {
      union { uint4 v; ushort_t us[8]; } uq, uk;
      uq.v = qv4; uk.v = kv4;
      float4 qa = {h2f(uq.us[0]), h2f(uq.us[1]), h2f(uq.us[2]), h2f(uq.us[3])};
      float4 qb = {h2f(uq.us[4]), h2f(uq.us[5]), h2f(uq.us[6]), h2f(uq.us[7])};
      float4 ka = {h2f(uk.us[0]), h2f(uk.us[1]), h2f(uk.us[2]), h2f(uk.us[3])};
      float4 kb = {h2f(uk.us[4]), h2f(uk.us[5]), h2f(uk.us[6]), h2f(uk.us[7])};
      float* dq = &sh[lrow * 36 + loct * 8];
      float* dk = &sh[2304 + lrow * 36 + loct * 8];
      *(float4*)dq = qa; *(float4*)(dq + 4) = qb;
      *(float4*)dk = ka; *(float4*)(dk + 4) = kb;
    }
    __syncthreads();
    if (p < 8) {  // prefetch next phase (hidden under compute)
      int n2 = n2base + (p + 1) * 64 + lrow;
      int o = n2 / 24, r = n2 - o * 24;
      const ushort_t* rp = basep + (size_t)o * N_ + r * THREEC + h * HD + loct * 8;
      qv4 = *(const uint4*)rp;
      kv4 = *(const uint4*)(rp + C_);
    }
    // per-channel square sums (thread owns column j over 8 rows)
#pragma unroll
    for (int i = 0; i < 8; ++i) {
      float qv = sh[(g8 * 8 + i) * 36 + j];
      float kv = sh[2304 + (g8 * 8 + i) * 36 + j];
      sqq = fmaf(qv, qv, sqq);
      sqk = fmaf(kv, kv, sqk);
    }
    // S[c][d] outer-product accumulation
#pragma unroll
    for (int i = 0; i < 16; ++i) {
      int n2l = tg * 16 + i;
      float4 q4 = *(const float4*)&sh[n2l * 36 + c0];
      float4 k4 = *(const float4*)&sh[2304 + n2l * 36 + d0];
      float q[4] = {q4.x, q4.y, q4.z, q4.w};
      float kk[4] = {k4.x, k4.y, k4.z, k4.w};
#pragma unroll
      for (int ii = 0; ii < 4; ++ii)
#pragma unroll
        for (int mm = 0; mm < 4; ++mm)
          acc[ii][mm] = fmaf(q[ii], kk[mm], acc[ii][mm]);
    }
  }
  __syncthreads();
#pragma unroll
  for (int ii = 0; ii < 4; ++ii)
#pragma unroll
    for (int mm = 0; mm < 4; ++mm)
      sh[tg * 1024 + (c0 + ii) * 32 + (d0 + mm)] = acc[ii][mm];
  sh[4608 + g8 * 32 + j] = sqq;
  sh[4864 + g8 * 32 + j] = sqk;
  __syncthreads();

  float* outp = Spart + (size_t)((b * HEADS + h) * CHUNKS + chunk) * 1088;
  for (int e = t; e < 1024; e += 256)
    outp[e] = sh[e] + sh[1024 + e] + sh[2048 + e] + sh[3072 + e];
  if (t < 32) {
    float s = 0.f;
#pragma unroll
    for (int g = 0; g < 8; ++g) s += sh[4608 + g * 32 + t];
    outp[1024 + t] = s;
  } else if (t < 64) {
    int jj = t - 32;
    float s = 0.f;
#pragma unroll
    for (int g = 0; g < 8; ++g) s += sh[4864 + g * 32 + jj];
    outp[1056 + jj] = s;
  }
}

// ---------------------------------------------------------------------------
// K3: reduce partials, softmax over d, then
// W2bf[b][co][h*32+d] = fp16( sum_c proj_w[co][c*6+h]*attn[c][d] ).
// grid (6, 8) = (h, b), block 256.
// ---------------------------------------------------------------------------
__global__ __launch_bounds__(256) void attn_final(
    const float* __restrict__ Spart, const float* __restrict__ temp,
    const float* __restrict__ proj_w, ushort_t* __restrict__ W2bf) {
  __shared__ float Sl[1024];
  __shared__ float invq[32], invk[32];
  __shared__ float Pl[192 * 33];
  int t = threadIdx.x;
  int h = blockIdx.x, b = blockIdx.y;
  const float* base = Spart + (size_t)((b * HEADS + h) * CHUNKS) * 1088;

  for (int e = t; e < 1024; e += 256) {
    float s = 0.f;
#pragma unroll
    for (int ch = 0; ch < CHUNKS; ++ch) s += base[ch * 1088 + e];
    Sl[e] = s;
  }
  if (t < 64) {
    int jj = t & 31;
    int off = 1024 + (t >> 5) * 32 + jj;
    float s = 0.f;
#pragma unroll
    for (int ch = 0; ch < CHUNKS; ++ch) s += base[ch * 1088 + off];
    float inv = 1.f / fmaxf(sqrtf(s), 1e-12f);
    if (t < 32) invq[jj] = inv; else invk[jj] = inv;
  }
  for (int e = t; e < 6144; e += 256) {
    int co = e >> 5, c = e & 31;
    Pl[co * 33 + c] = proj_w[(size_t)co * C_ + c * HEADS + h];
  }
  __syncthreads();

  {
    int c = t >> 3, l8 = t & 7;
    float tmpv = temp[h];
    float iq = invq[c];
    float lg[4];
#pragma unroll
    for (int m = 0; m < 4; ++m) {
      int d = l8 * 4 + m;
      lg[m] = Sl[c * 32 + d] * iq * invk[d] * tmpv;
    }
    float mx = fmaxf(fmaxf(lg[0], lg[1]), fmaxf(lg[2], lg[3]));
    for (int off = 1; off < 8; off <<= 1) mx = fmaxf(mx, __shfl_xor(mx, off, 8));
    float ex[4]; float ssum = 0.f;
#pragma unroll
    for (int m = 0; m < 4; ++m) { ex[m] = __expf(lg[m] - mx); ssum += ex[m]; }
    for (int off = 1; off < 8; off <<= 1) ssum += __shfl_xor(ssum, off, 8);
    float inv = 1.f / ssum;
#pragma unroll
    for (int m = 0; m < 4; ++m) Sl[c * 32 + l8 * 4 + m] = ex[m] * inv;
  }
  __syncthreads();

  // W2 in A-operand layout: [co][j=h*32+d], fp16
  for (int e2 = t; e2 < 6144; e2 += 256) {
    int co = e2 >> 5, d = e2 & 31;
    float s = 0.f;
#pragma unroll
    for (int c = 0; c < 32; ++c)
      s = fmaf(Pl[co * 33 + c], Sl[c * 32 + d], s);
    W2bf[((size_t)b * C_ + co) * C_ + h * HD + d] = f2h(s);
  }
}

// ---------------------------------------------------------------------------
// K4: MFMA GEMM y[b][co][n2] = proj_b[co] + sum_j W2[b][co][j] * V[b][n2][j].
// V[b][n2][j] = qkv[b][ (n2/24)*N + (n2%24)*576 + 384 + j ] (scrambled layout,
// consistent permutation of the spatial index across the whole pipeline).
// RESTRUCTURED like K1: one n2-tile (BN=128) staged once, loop over all 3
// o-blocks with A double-buffered from L2-resident W2bf. grid 864 = 8*108.
// ---------------------------------------------------------------------------
__global__ __launch_bounds__(256) void proj_mfma(
    const ushort_t* __restrict__ qkv, const ushort_t* __restrict__ W2bf,
    const float* __restrict__ pb, float* __restrict__ y) {
  __shared__ ushort_t Bs[128 * LROW];  // [n2][j]
  int t = threadIdx.x;
  int bid = blockIdx.x;
  int l = (bid & 7) * 108 + (bid >> 3);
  int n2_0 = (l % 108) * 128;
  int b = l / 108;
  int w = t >> 6, lane = t & 63;
  int ln16 = lane & 15, q4 = lane >> 4;
  int mrow = (w >> 1) * 32, ncol = (w & 1) * 64;

  const ushort_t* basep = qkv + (size_t)b * THREEC * N_;

  uint4 breg2[12]; int brow[12], bu[12];
#pragma unroll
  for (int j = 0; j < 12; ++j) {
    int f = (w * 12 + j) * 64 + lane;
    rowperm(f, brow[j], bu[j]);
    int n2 = n2_0 + brow[j];
    int o = n2 / 24, r2 = n2 - o * 24;
    breg2[j] = *(const uint4*)(basep + (size_t)o * N_ + r2 * THREEC + 384 + bu[j] * 8);
  }
#pragma unroll
  for (int j = 0; j < 12; ++j)
    *(uint4*)&Bs[brow[j] * LROW + bu[j] * 8] = breg2[j];

  const ushort_t* Abase0 = W2bf + ((size_t)b * C_ + mrow + ln16) * C_ + q4 * 8;
  half8 af[2][12];
#pragma unroll
  for (int kk = 0; kk < 6; ++kk)
#pragma unroll
    for (int mi = 0; mi < 2; ++mi)
      af[0][kk * 2 + mi] = *(const half8*)(Abase0 + mi * 16 * C_ + kk * 32);

  __syncthreads();  // only barrier

#pragma unroll
  for (int it = 0; it < 3; ++it) {
    int o0 = it * 64;
    int cur = it & 1, nxt = cur ^ 1;
    if (it < 2) {
      const ushort_t* An = Abase0 + (size_t)(o0 + 64) * C_;
#pragma unroll
      for (int kk = 0; kk < 6; ++kk)
#pragma unroll
        for (int mi = 0; mi < 2; ++mi)
          af[nxt][kk * 2 + mi] = *(const half8*)(An + mi * 16 * C_ + kk * 32);
    }

    float breg[2][4];
#pragma unroll
    for (int mi = 0; mi < 2; ++mi)
#pragma unroll
      for (int r = 0; r < 4; ++r)
        breg[mi][r] = pb[o0 + mrow + mi * 16 + q4 * 4 + r];

    f32x4 acc[2][4];
#pragma unroll
    for (int mi = 0; mi < 2; ++mi)
#pragma unroll
      for (int ni = 0; ni < 4; ++ni) acc[mi][ni] = (f32x4){0.f, 0.f, 0.f, 0.f};

#pragma unroll
    for (int kk = 0; kk < 6; ++kk) {
      int k0 = kk * 32 + q4 * 8;
      half8 bb[4];
#pragma unroll
      for (int ni = 0; ni < 4; ++ni)
        bb[ni] = *(const half8*)&Bs[(ncol + ni * 16 + ln16) * LROW + k0];
#pragma unroll
      for (int mi = 0; mi < 2; ++mi)
#pragma unroll
        for (int ni = 0; ni < 4; ++ni)
          acc[mi][ni] = __builtin_amdgcn_mfma_f32_16x16x32_f16(
              af[cur][kk * 2 + mi], bb[ni], acc[mi][ni], 0, 0, 0);
    }

    // epilogue: fp32 y, 16-lane-contiguous 64B stores
#pragma unroll
    for (int mi = 0; mi < 2; ++mi)
#pragma unroll
      for (int ni = 0; ni < 4; ++ni)
#pragma unroll
        for (int r = 0; r < 4; ++r) {
          int co_l = o0 + mrow + mi * 16 + q4 * 4 + r;
          int n_l = ncol + ni * 16 + ln16;
          y[((size_t)b * C_ + co_l) * N_ + n2_0 + n_l] =
              acc[mi][ni][r] + breg[mi][r];
        }
  }
}

// ---------------------------------------------------------------------------
extern "C" void kernel_launch(void* const* d_in, const int* in_sizes, int n_in,
                              void* d_out, int out_size, void* d_ws, size_t ws_size,
                              hipStream_t stream) {
  const float* x      = (const float*)d_in[0];
  const float* qkv_w  = (const float*)d_in[1];
  const float* qkv_b  = (const float*)d_in[2];
  const float* temp   = (const float*)d_in[3];
  const float* proj_w = (const float*)d_in[4];
  const float* proj_b = (const float*)d_in[5];
  float* y = (float*)d_out;

  // ws: qkv fp16 127.4MB | xT fp16 42.5MB | W2 0.59MB | w 0.22MB.
  // Spart (5.0MB, 24 chunks) ALIASES xT: xT is dead after K1, Spart is
  // written by K2 (after K1) and read by K3 -> no lifetime overlap.
  char* wp = (char*)d_ws;
  ushort_t* qkv  = (ushort_t*)wp;  wp += (size_t)B_ * THREEC * N_ * 2;
  ushort_t* xT   = (ushort_t*)wp;  wp += (size_t)B_ * N_ * C_ * 2;
  ushort_t* W2bf = (ushort_t*)wp;  wp += (size_t)B_ * C_ * C_ * 2;
  ushort_t* wbf  = (ushort_t*)wp;
  float* Spart   = (float*)xT;     // alias, 48*24*1088*4 = 5.0MB <= 42.5MB

  wconv<<<54, 256, 0, stream>>>(qkv_w, wbf);
  xt_conv<<<dim3(216, B_), 256, 0, stream>>>(x, xT);
  qkv_gemm_mfma<<<864, 256, 0, stream>>>(wbf, xT, qkv_b, qkv);
  attn_partial<<<dim3(CHUNKS, HEADS, B_), 256, 0, stream>>>(qkv, Spart);
  attn_final<<<dim3(HEADS, B_), 256, 0, stream>>>(Spart, temp, proj_w, W2bf);
  proj_mfma<<<864, 256, 0, stream>>>(qkv, W2bf, proj_b, y);
}

// Round 5
// 307.283 us; speedup vs baseline: 1.1695x; 1.1695x over previous
//
#include <hip/hip_runtime.h>

#define B_ 8
#define C_ 192
#define N_ 13824     // 24^3
#define HEADS 6
#define HD 32
#define THREEC 576
#define CHUNKS 24    // K2 n-chunks per (b,h): 576 n each, 9 phases of 64

typedef unsigned short ushort_t;
typedef unsigned int uint_t;
typedef __attribute__((ext_vector_type(8))) _Float16 half8;
typedef __attribute__((ext_vector_type(4))) float f32x4;

// fp16 (not bf16): same MFMA rate / bytes / layout, 8x lower rounding error.
__device__ __forceinline__ float h2f(ushort_t u) {
  union { ushort_t u; _Float16 h; } c; c.u = u; return (float)c.h;
}
__device__ __forceinline__ ushort_t f2h(float f) {
  union { _Float16 h; ushort_t u; } c; c.h = (_Float16)f; return c.u;  // v_cvt_f16_f32, RNE
}

// Async global->LDS, 16B per lane. LDS dest must be wave-uniform base; HW adds
// lane*16. Source is per-lane (this is where the swizzle goes).
__device__ __forceinline__ void gload_lds16(const ushort_t* g, ushort_t* l) {
  __builtin_amdgcn_global_load_lds(
      (const __attribute__((address_space(1))) void*)g,
      (__attribute__((address_space(3))) void*)l, 16, 0, 0);
}

// B-tile swizzle (m201 both-sides-or-neither): LDS is linear [128][192] fp16
// (row = 24 16B-units). Unit u of row r holds SOURCE unit u^=(r&7) (XOR within
// 8-unit groups; involution). Fragment reads apply the same XOR; since a frag
// read's 16 lanes have rr&7 = ln16&7 = lane-constant, the read addr is cheap
// and the bank pattern is 8 banks x 4 dwords x 2 lanes = conflict-free.
__device__ __forceinline__ int swz_u(int u, int r) {
  return (u & ~7) | ((u & 7) ^ (r & 7));
}

// ---------------------------------------------------------------------------
// K0a: qkv_w fp32 -> fp16. grid 54.
// ---------------------------------------------------------------------------
__global__ __launch_bounds__(256) void wconv(const float* __restrict__ w,
                                             ushort_t* __restrict__ wbf) {
  int idx = (blockIdx.x * 256 + threadIdx.x) * 8;  // 54*256*8 = 110592
  float4 v0 = *(const float4*)&w[idx];
  float4 v1 = *(const float4*)&w[idx + 4];
  union { ushort_t us[8]; uint4 v; } pk;
  pk.us[0] = f2h(v0.x); pk.us[1] = f2h(v0.y); pk.us[2] = f2h(v0.z); pk.us[3] = f2h(v0.w);
  pk.us[4] = f2h(v1.x); pk.us[5] = f2h(v1.y); pk.us[6] = f2h(v1.z); pk.us[7] = f2h(v1.w);
  *(uint4*)&wbf[idx] = pk.v;
}

// ---------------------------------------------------------------------------
// K0b: transpose+convert x[b][c][n] fp32 -> xT[b][n][c] fp16. grid (216, 8).
// ---------------------------------------------------------------------------
__global__ __launch_bounds__(256) void xt_conv(const float* __restrict__ x,
                                               ushort_t* __restrict__ xT) {
  __shared__ ushort_t tile[64 * 200];
  int t = threadIdx.x;
  int n0 = blockIdx.x * 64, b = blockIdx.y;
  const float* xb = x + (size_t)b * C_ * N_;
  int n4 = t & 15, cp = t >> 4;
#pragma unroll
  for (int it = 0; it < 6; ++it) {
    int c = (cp + it * 16) * 2;
    float4 v0 = *(const float4*)&xb[(size_t)c * N_ + n0 + n4 * 4];
    float4 v1 = *(const float4*)&xb[(size_t)(c + 1) * N_ + n0 + n4 * 4];
    float a0[4] = {v0.x, v0.y, v0.z, v0.w};
    float a1[4] = {v1.x, v1.y, v1.z, v1.w};
#pragma unroll
    for (int i = 0; i < 4; ++i) {
      uint_t wd = (uint_t)f2h(a0[i]) | ((uint_t)f2h(a1[i]) << 16);
      *(uint_t*)&tile[(n4 * 4 + i) * 200 + c] = wd;
    }
  }
  __syncthreads();
  ushort_t* xTb = xT + ((size_t)b * N_ + n0) * C_;
  int r = t >> 2, q = t & 3;
#pragma unroll
  for (int j = 0; j < 6; ++j) {
    int chunk = q * 6 + j;
    uint4 v = *(const uint4*)&tile[r * 200 + chunk * 8];
    *(uint4*)&xTb[r * 192 + chunk * 8] = v;
  }
}

// ---------------------------------------------------------------------------
// K1: MFMA fp16 GEMM: qkv[b][o][n] = sum_c wbf[o][c]*xT[b][n][c] + bias[o].
// One-shot (R2 skeleton, the best-measured): BM=64, BN=128, grid 7776 = 8*972
// XCD-chunked (o fastest -> 9 sharers of each xT tile on one XCD's L2).
// v5: B staged via global_load_lds w16 + XOR swizzle (no VGPR roundtrip, no
// ds_writes, conflict-free frag reads); no-shfl epilogue; setprio on MFMAs.
// ---------------------------------------------------------------------------
__global__ __launch_bounds__(256) void qkv_gemm_mfma(
    const ushort_t* __restrict__ wbf, const ushort_t* __restrict__ xT,
    const float* __restrict__ bias, ushort_t* __restrict__ qkv) {
  __shared__ ushort_t Bs[128 * 192];  // linear, 48KB, swizzled content
  int t = threadIdx.x;
  int bid = blockIdx.x;
  int l = (bid & 7) * 972 + (bid >> 3);
  int o0 = (l % 9) * 64;
  int rest = l / 9;
  int n0 = (rest % 108) * 128;
  int b = rest / 108;
  int w = t >> 6, lane = t & 63;
  int ln16 = lane & 15, q4 = lane >> 4;
  int mrow = (w >> 1) * 32, ncol = (w & 1) * 64;

  const ushort_t* Bsrc = xT + ((size_t)b * N_ + n0) * C_;

  // ---- async stage B: 3072 16B units; source pre-swizzled per lane ----
#pragma unroll
  for (int j = 0; j < 12; ++j) {
    int f = (w * 12 + j) * 64 + lane;   // linear LDS unit index
    int r = f / 24, u = f - r * 24;
    gload_lds16(Bsrc + r * C_ + swz_u(u, r) * 8, &Bs[(w * 12 + j) * 512]);
  }

  // ---- A fragments direct from global (wbf L2-resident) ----
  const ushort_t* Abase = wbf + (size_t)(o0 + mrow + ln16) * C_ + q4 * 8;
  half8 afrag[6][2];
#pragma unroll
  for (int kk = 0; kk < 6; ++kk)
#pragma unroll
    for (int mi = 0; mi < 2; ++mi)
      afrag[kk][mi] = *(const half8*)(Abase + mi * 16 * C_ + kk * 32);

  float breg[2][4];
#pragma unroll
  for (int mi = 0; mi < 2; ++mi)
#pragma unroll
    for (int r = 0; r < 4; ++r)
      breg[mi][r] = bias[o0 + mrow + mi * 16 + q4 * 4 + r];

  f32x4 acc[2][4];
#pragma unroll
  for (int mi = 0; mi < 2; ++mi)
#pragma unroll
    for (int ni = 0; ni < 4; ++ni) acc[mi][ni] = (f32x4){0.f, 0.f, 0.f, 0.f};

  // swizzled frag-read units: rr&7 == ln16&7 for every frag row this lane reads
  int ur[6];
#pragma unroll
  for (int kk = 0; kk < 6; ++kk) ur[kk] = swz_u(kk * 4 + q4, ln16);

  __syncthreads();

  __builtin_amdgcn_s_setprio(1);
#pragma unroll
  for (int kk = 0; kk < 6; ++kk) {
    half8 bb[4];
#pragma unroll
    for (int ni = 0; ni < 4; ++ni)
      bb[ni] = *(const half8*)&Bs[(ncol + ni * 16 + ln16) * 192 + ur[kk] * 8];
#pragma unroll
    for (int mi = 0; mi < 2; ++mi)
#pragma unroll
      for (int ni = 0; ni < 4; ++ni)
        acc[mi][ni] = __builtin_amdgcn_mfma_f32_16x16x32_f16(
            afrag[kk][mi], bb[ni], acc[mi][ni], 0, 0, 0);
  }
  __builtin_amdgcn_s_setprio(0);

  // ---- epilogue: +bias, fp16, direct 2B stores (no shfl) ----
#pragma unroll
  for (int mi = 0; mi < 2; ++mi)
#pragma unroll
    for (int ni = 0; ni < 4; ++ni)
#pragma unroll
      for (int r = 0; r < 4; ++r) {
        float v = acc[mi][ni][r] + breg[mi][r];
        int o_l = o0 + mrow + mi * 16 + q4 * 4 + r;
        int n_l = ncol + ni * 16 + ln16;
        qkv[(size_t)(b * THREEC + o_l) * N_ + n0 + n_l] = f2h(v);
      }
}

// ---------------------------------------------------------------------------
// K2: per (b,h,chunk): partial S[c][d], nq[c], nk[d]. grid (24, 6, 8).
// (R3 form — best-measured "others" config.)
// ---------------------------------------------------------------------------
__global__ __launch_bounds__(256) void attn_partial(
    const ushort_t* __restrict__ qkv, float* __restrict__ Spart) {
  __shared__ float sh[4608];
  int t = threadIdx.x;
  int chunk = blockIdx.x, h = blockIdx.y, b = blockIdx.z;
  int j = t & 31, g8 = t >> 5;
  int tg = t >> 6, tl = t & 63;
  int c0 = (tl & 7) * 4, d0 = (tl >> 3) * 4;
  float acc[4][4];
#pragma unroll
  for (int i = 0; i < 4; ++i)
#pragma unroll
    for (int m = 0; m < 4; ++m) acc[i][m] = 0.f;
  float sqq = 0.f, sqk = 0.f;
  const ushort_t* basep = qkv + (size_t)b * THREEC * N_;
  int n2base = chunk * 576;

  for (int p = 0; p < 9; ++p) {
    __syncthreads();
#pragma unroll
    for (int i = 0; i < 8; ++i) {
      int n2l = g8 * 8 + i;
      int n2 = n2base + p * 64 + n2l;
      int o = n2 / 24, r = n2 - o * 24;
      const ushort_t* rp = basep + (size_t)o * N_ + r * THREEC + h * HD + j;
      float qv = h2f(rp[0]);
      float kv = h2f(rp[C_]);
      sh[n2l * 32 + j] = qv;
      sh[2048 + n2l * 32 + j] = kv;
      sqq = fmaf(qv, qv, sqq);
      sqk = fmaf(kv, kv, sqk);
    }
    __syncthreads();
#pragma unroll
    for (int i = 0; i < 16; ++i) {
      int n2l = tg * 16 + i;
      float4 q4 = *(const float4*)&sh[n2l * 32 + c0];
      float4 k4 = *(const float4*)&sh[2048 + n2l * 32 + d0];
      float q[4] = {q4.x, q4.y, q4.z, q4.w};
      float kk[4] = {k4.x, k4.y, k4.z, k4.w};
#pragma unroll
      for (int ii = 0; ii < 4; ++ii)
#pragma unroll
        for (int mm = 0; mm < 4; ++mm)
          acc[ii][mm] = fmaf(q[ii], kk[mm], acc[ii][mm]);
    }
  }
  __syncthreads();
#pragma unroll
  for (int ii = 0; ii < 4; ++ii)
#pragma unroll
    for (int mm = 0; mm < 4; ++mm)
      sh[tg * 1024 + (c0 + ii) * 32 + (d0 + mm)] = acc[ii][mm];
  sh[4096 + g8 * 32 + j] = sqq;
  sh[4352 + g8 * 32 + j] = sqk;
  __syncthreads();

  float* outp = Spart + (size_t)((b * HEADS + h) * CHUNKS + chunk) * 1088;
  for (int e = t; e < 1024; e += 256)
    outp[e] = sh[e] + sh[1024 + e] + sh[2048 + e] + sh[3072 + e];
  if (t < 32) {
    float s = 0.f;
#pragma unroll
    for (int g = 0; g < 8; ++g) s += sh[4096 + g * 32 + t];
    outp[1024 + t] = s;
  } else if (t < 64) {
    int jj = t - 32;
    float s = 0.f;
#pragma unroll
    for (int g = 0; g < 8; ++g) s += sh[4352 + g * 32 + jj];
    outp[1056 + jj] = s;
  }
}

// ---------------------------------------------------------------------------
// K3: reduce partials, softmax over d, then
// W2bf[b][co][h*32+d] = fp16( sum_c proj_w[co][c*6+h]*attn[c][d] ).
// grid (6, 8) = (h, b), block 256.
// ---------------------------------------------------------------------------
__global__ __launch_bounds__(256) void attn_final(
    const float* __restrict__ Spart, const float* __restrict__ temp,
    const float* __restrict__ proj_w, ushort_t* __restrict__ W2bf) {
  __shared__ float Sl[1024];
  __shared__ float invq[32], invk[32];
  __shared__ float Pl[192 * 33];
  int t = threadIdx.x;
  int h = blockIdx.x, b = blockIdx.y;
  const float* base = Spart + (size_t)((b * HEADS + h) * CHUNKS) * 1088;

  for (int e = t; e < 1024; e += 256) {
    float s = 0.f;
#pragma unroll
    for (int ch = 0; ch < CHUNKS; ++ch) s += base[ch * 1088 + e];
    Sl[e] = s;
  }
  if (t < 64) {
    int jj = t & 31;
    int off = 1024 + (t >> 5) * 32 + jj;
    float s = 0.f;
#pragma unroll
    for (int ch = 0; ch < CHUNKS; ++ch) s += base[ch * 1088 + off];
    float inv = 1.f / fmaxf(sqrtf(s), 1e-12f);
    if (t < 32) invq[jj] = inv; else invk[jj] = inv;
  }
  for (int e = t; e < 6144; e += 256) {
    int co = e >> 5, c = e & 31;
    Pl[co * 33 + c] = proj_w[(size_t)co * C_ + c * HEADS + h];
  }
  __syncthreads();

  {
    int c = t >> 3, l8 = t & 7;
    float tmpv = temp[h];
    float iq = invq[c];
    float lg[4];
#pragma unroll
    for (int m = 0; m < 4; ++m) {
      int d = l8 * 4 + m;
      lg[m] = Sl[c * 32 + d] * iq * invk[d] * tmpv;
    }
    float mx = fmaxf(fmaxf(lg[0], lg[1]), fmaxf(lg[2], lg[3]));
    for (int off = 1; off < 8; off <<= 1) mx = fmaxf(mx, __shfl_xor(mx, off, 8));
    float ex[4]; float ssum = 0.f;
#pragma unroll
    for (int m = 0; m < 4; ++m) { ex[m] = __expf(lg[m] - mx); ssum += ex[m]; }
    for (int off = 1; off < 8; off <<= 1) ssum += __shfl_xor(ssum, off, 8);
    float inv = 1.f / ssum;
#pragma unroll
    for (int m = 0; m < 4; ++m) Sl[c * 32 + l8 * 4 + m] = ex[m] * inv;
  }
  __syncthreads();

  // W2 in A-operand layout: [co][j=h*32+d], fp16
  for (int e2 = t; e2 < 6144; e2 += 256) {
    int co = e2 >> 5, d = e2 & 31;
    float s = 0.f;
#pragma unroll
    for (int c = 0; c < 32; ++c)
      s = fmaf(Pl[co * 33 + c], Sl[c * 32 + d], s);
    W2bf[((size_t)b * C_ + co) * C_ + h * HD + d] = f2h(s);
  }
}

// ---------------------------------------------------------------------------
// K4: MFMA GEMM y[b][co][n2] = proj_b[co] + sum_j W2[b][co][j] * V[b][n2][j].
// V[b][n2][j] = qkv[b][ (n2/24)*N + (n2%24)*576 + 384 + j ] (reshape scramble;
// per-lane source addressing feeds global_load_lds directly).
// One-shot BM=64, BN=128, grid 2592 = 8*324 (o fastest within XCD chunk).
// Same v5 treatment as K1.
// ---------------------------------------------------------------------------
__global__ __launch_bounds__(256) void proj_mfma(
    const ushort_t* __restrict__ qkv, const ushort_t* __restrict__ W2bf,
    const float* __restrict__ pb, float* __restrict__ y) {
  __shared__ ushort_t Bs[128 * 192];  // linear, swizzled content
  int t = threadIdx.x;
  int bid = blockIdx.x;
  int l = (bid & 7) * 324 + (bid >> 3);
  int o0 = (l % 3) * 64;
  int rest = l / 3;
  int n2_0 = (rest % 108) * 128;
  int b = rest / 108;
  int w = t >> 6, lane = t & 63;
  int ln16 = lane & 15, q4 = lane >> 4;
  int mrow = (w >> 1) * 32, ncol = (w & 1) * 64;

  const ushort_t* basep = qkv + (size_t)b * THREEC * N_;

#pragma unroll
  for (int j = 0; j < 12; ++j) {
    int f = (w * 12 + j) * 64 + lane;
    int r = f / 24, u = f - r * 24;
    int n2 = n2_0 + r;
    int o = n2 / 24, r2 = n2 - o * 24;
    gload_lds16(basep + (size_t)o * N_ + r2 * THREEC + 384 + swz_u(u, r) * 8,
                &Bs[(w * 12 + j) * 512]);
  }

  // A fragments direct from global (W2bf per-b = 74 KB, L2-resident)
  const ushort_t* Abase = W2bf + ((size_t)b * C_ + o0 + mrow + ln16) * C_ + q4 * 8;
  half8 afrag[6][2];
#pragma unroll
  for (int kk = 0; kk < 6; ++kk)
#pragma unroll
    for (int mi = 0; mi < 2; ++mi)
      afrag[kk][mi] = *(const half8*)(Abase + mi * 16 * C_ + kk * 32);

  float breg[2][4];
#pragma unroll
  for (int mi = 0; mi < 2; ++mi)
#pragma unroll
    for (int r = 0; r < 4; ++r)
      breg[mi][r] = pb[o0 + mrow + mi * 16 + q4 * 4 + r];

  f32x4 acc[2][4];
#pragma unroll
  for (int mi = 0; mi < 2; ++mi)
#pragma unroll
    for (int ni = 0; ni < 4; ++ni) acc[mi][ni] = (f32x4){0.f, 0.f, 0.f, 0.f};

  int ur[6];
#pragma unroll
  for (int kk = 0; kk < 6; ++kk) ur[kk] = swz_u(kk * 4 + q4, ln16);

  __syncthreads();

  __builtin_amdgcn_s_setprio(1);
#pragma unroll
  for (int kk = 0; kk < 6; ++kk) {
    half8 bb[4];
#pragma unroll
    for (int ni = 0; ni < 4; ++ni)
      bb[ni] = *(const half8*)&Bs[(ncol + ni * 16 + ln16) * 192 + ur[kk] * 8];
#pragma unroll
    for (int mi = 0; mi < 2; ++mi)
#pragma unroll
      for (int ni = 0; ni < 4; ++ni)
        acc[mi][ni] = __builtin_amdgcn_mfma_f32_16x16x32_f16(
            afrag[kk][mi], bb[ni], acc[mi][ni], 0, 0, 0);
  }
  __builtin_amdgcn_s_setprio(0);

  // epilogue: fp32 y, 16-lane-contiguous 64B stores
#pragma unroll
  for (int mi = 0; mi < 2; ++mi)
#pragma unroll
    for (int ni = 0; ni < 4; ++ni)
#pragma unroll
      for (int r = 0; r < 4; ++r) {
        int co_l = o0 + mrow + mi * 16 + q4 * 4 + r;
        int n_l = ncol + ni * 16 + ln16;
        y[((size_t)b * C_ + co_l) * N_ + n2_0 + n_l] =
            acc[mi][ni][r] + breg[mi][r];
      }
}

// ---------------------------------------------------------------------------
extern "C" void kernel_launch(void* const* d_in, const int* in_sizes, int n_in,
                              void* d_out, int out_size, void* d_ws, size_t ws_size,
                              hipStream_t stream) {
  const float* x      = (const float*)d_in[0];
  const float* qkv_w  = (const float*)d_in[1];
  const float* qkv_b  = (const float*)d_in[2];
  const float* temp   = (const float*)d_in[3];
  const float* proj_w = (const float*)d_in[4];
  const float* proj_b = (const float*)d_in[5];
  float* y = (float*)d_out;

  // ws: qkv fp16 127.4MB | xT fp16 42.5MB | W2 0.59MB | w 0.22MB.
  // Spart (5.0MB, 24 chunks) ALIASES xT: xT is dead after K1, Spart is
  // written by K2 (after K1) and read by K3 -> no lifetime overlap.
  char* wp = (char*)d_ws;
  ushort_t* qkv  = (ushort_t*)wp;  wp += (size_t)B_ * THREEC * N_ * 2;
  ushort_t* xT   = (ushort_t*)wp;  wp += (size_t)B_ * N_ * C_ * 2;
  ushort_t* W2bf = (ushort_t*)wp;  wp += (size_t)B_ * C_ * C_ * 2;
  ushort_t* wbf  = (ushort_t*)wp;
  float* Spart   = (float*)xT;     // alias, 48*24*1088*4 = 5.0MB <= 42.5MB

  wconv<<<54, 256, 0, stream>>>(qkv_w, wbf);
  xt_conv<<<dim3(216, B_), 256, 0, stream>>>(x, xT);
  qkv_gemm_mfma<<<7776, 256, 0, stream>>>(wbf, xT, qkv_b, qkv);
  attn_partial<<<dim3(CHUNKS, HEADS, B_), 256, 0, stream>>>(qkv, Spart);
  attn_final<<<dim3(HEADS, B_), 256, 0, stream>>>(Spart, temp, proj_w, W2bf);
  proj_mfma<<<2592, 256, 0, stream>>>(qkv, W2bf, proj_b, y);
}